// Round 11
// baseline (467.729 us; speedup 1.0000x reference)
//
#include <hip/hip_runtime.h>
#include <math.h>

// Problem constants (reference: VOCAB=10000, HID=256, B=64, T=64)
#define VOCABN 10000
#define HIDN   256
#define GATES  1024   // 4*HID
#define BN     64
#define TN     64
#define BT     4096   // B*T
#define NCT    625    // vocab col-tiles of 16 (10000 = 625*16 exactly)

typedef unsigned int       u32;
typedef unsigned short     u16;
typedef unsigned long long u64;
typedef float v4f __attribute__((ext_vector_type(4)));
typedef short v8s __attribute__((ext_vector_type(8)));

__device__ __forceinline__ float bf2f(u16 u) {
    return __uint_as_float(((u32)u) << 16);
}
__device__ __forceinline__ u16 f2bf(float f) {          // round-to-nearest-even
    u32 u = __float_as_uint(f);
    u += 0x7FFFu + ((u >> 16) & 1u);
    return (u16)(u >> 16);
}
__device__ __forceinline__ float fast_sigmoid(float x) {
    return 1.0f / (1.0f + __expf(-x));
}
__device__ __forceinline__ float fast_tanh(float x) {
    float e = __expf(-2.0f * fabsf(x));
    float t = (1.0f - e) / (1.0f + e);
    return copysignf(t, x);
}
__device__ __forceinline__ u64 llc_load(const u64* p) {
    return __hip_atomic_load(p, __ATOMIC_RELAXED, __HIP_MEMORY_SCOPE_AGENT);
}
__device__ __forceinline__ void llc_store(u64* p, u64 v) {
    __hip_atomic_store(p, v, __ATOMIC_RELAXED, __HIP_MEMORY_SCOPE_AGENT);
}
__device__ __forceinline__ float llc_loadf(const float* p) {
    return __hip_atomic_load(p, __ATOMIC_RELAXED, __HIP_MEMORY_SCOPE_AGENT);
}
__device__ __forceinline__ void llc_storef(float* p, float v) {
    __hip_atomic_store(p, v, __ATOMIC_RELAXED, __HIP_MEMORY_SCOPE_AGENT);
}
__device__ __forceinline__ u32 cnt_add(u32* p) {
    return __hip_atomic_fetch_add(p, 1u, __ATOMIC_RELAXED,
                                  __HIP_MEMORY_SCOPE_AGENT);
}
__device__ __forceinline__ u32 cnt_read(u32* p) {
    return __hip_atomic_load(p, __ATOMIC_RELAXED, __HIP_MEMORY_SCOPE_AGENT);
}

// ---------------------------------------------------------------------------
// fp32 [HIDN][ncols] tile c -> bf16 MFMA B-fragment layout [c][8 q][64 l][8].
// Fragment (c,q), lane l holds B[k = q*32 + (l>>4)*8 + j][n = c*16 + (l&15)].
// Writes via llc_store: same-kernel consumers on other XCDs read LLC-fresh.
// ---------------------------------------------------------------------------
__device__ __forceinline__ void wfrag_dev(
    const float* __restrict__ src, u16* __restrict__ dst, int ncols, int c,
    int t, u16 lt[HIDN][16])
{
    const float* s = src + (size_t)t * ncols + c * 16;
    #pragma unroll
    for (int j4 = 0; j4 < 4; ++j4) {
        float4 v = *(const float4*)(s + j4 * 4);
        lt[t][j4*4+0] = f2bf(v.x);
        lt[t][j4*4+1] = f2bf(v.y);
        lt[t][j4*4+2] = f2bf(v.z);
        lt[t][j4*4+3] = f2bf(v.w);
    }
    __syncthreads();
    #pragma unroll
    for (int h = 0; h < 2; ++h) {
        int f = t + h * 256;             // frag id = q*64 + l
        int q = f >> 6, l = f & 63;
        int m = l & 15, kb = q * 32 + ((l >> 4) & 3) * 8;
        u32 w[4];
        #pragma unroll
        for (int j = 0; j < 4; ++j)
            w[j] = (u32)lt[kb + 2*j][m] | ((u32)lt[kb + 2*j + 1][m] << 16);
        u64* d = (u64*)(dst + (((size_t)c * 8 + q) * 64 + l) * 8);
        llc_store(d,     (u64)w[0] | ((u64)w[1] << 32));
        llc_store(d + 1, (u64)w[2] | ((u64)w[3] << 32));
    }
}

// ---------------------------------------------------------------------------
// PRE kernel (384 blocks):
//   0..63   : W_lstm x-part -> Wxf (llc_store), then bump wxdone
//   64..127 : W_lstm h-part -> Whf (llc_store; plstm is a later launch)
//   128..383: xgates — spin wxdone==64, then gates_x = E[idx]@W_x + b (fp32)
// No deadlock: producers never wait; consumers spin on an LLC counter.
// ---------------------------------------------------------------------------
__global__ __launch_bounds__(256) void k_pre(
    const float* __restrict__ W_lstm,
    const int*   __restrict__ idx,   // [BT]
    const float* __restrict__ E,     // [VOCAB][HIDN]
    const float* __restrict__ bl,    // [GATES]
    u16*         __restrict__ Wxf,   // [64][8][64][8]
    u16*         __restrict__ Whf,   // [64][8][64][8]
    float*       __restrict__ gx,    // [BT][GATES]
    u32*                      wxdone)
{
    __shared__ u16 lt[HIDN][16];
    const int bid = blockIdx.x;
    const int tid = threadIdx.x;

    if (bid < 64) {
        wfrag_dev(W_lstm, Wxf, GATES, bid, tid, lt);
        __syncthreads();                 // drain llc_stores (vmcnt(0)/wave)
        if (tid == 0) cnt_add(wxdone);
        return;
    }
    if (bid < 128) {
        wfrag_dev(W_lstm + (size_t)HIDN * GATES, Whf, GATES, bid - 64, tid, lt);
        return;
    }

    // ---- xgates role ----
    if (tid == 0)
        while (cnt_read(wxdone) < 64u) __builtin_amdgcn_s_sleep(8);
    __syncthreads();

    const int r0   = (bid - 128) * 16;
    const int w    = tid >> 6, lane = tid & 63;
    const int m    = lane & 15, quad = lane >> 4;

    v8s a[8];
    {
        const float* e = E + (size_t)idx[r0 + m] * HIDN + quad * 8;
        #pragma unroll
        for (int q = 0; q < 8; ++q) {
            float4 x0 = *(const float4*)(e + q * 32);
            float4 x1 = *(const float4*)(e + q * 32 + 4);
            uint4 t4 = make_uint4(
                (u32)f2bf(x0.x) | ((u32)f2bf(x0.y) << 16),
                (u32)f2bf(x0.z) | ((u32)f2bf(x0.w) << 16),
                (u32)f2bf(x1.x) | ((u32)f2bf(x1.y) << 16),
                (u32)f2bf(x1.z) | ((u32)f2bf(x1.w) << 16));
            a[q] = *(v8s*)&t4;
        }
    }
    for (int c = w; c < GATES / 16; c += 4) {
        v4f acc = {0.f, 0.f, 0.f, 0.f};
        #pragma unroll
        for (int q = 0; q < 8; ++q) {
            // Wxf just written via llc_store; no L2 copies exist -> plain
            // loads fetch from LLC (fresh) and are L2-cacheable afterwards.
            union { u64 d[2]; v8s v; } bu;
            const u64* bp = (const u64*)(Wxf + (((size_t)c * 8 + q) * 64 + lane) * 8);
            bu.d[0] = bp[0]; bu.d[1] = bp[1];
            acc = __builtin_amdgcn_mfma_f32_16x16x32_bf16(a[q], bu.v, acc, 0, 0, 0);
        }
        const int col = c * 16 + m;
        const float bv = bl[col];
        #pragma unroll
        for (int r = 0; r < 4; ++r)   // D: col=lane&15, row=quad*4+r (m89/m91)
            gx[(size_t)(r0 + quad * 4 + r) * GATES + col] = acc[r] + bv;
    }
}

// ---------------------------------------------------------------------------
// Kernel 2 (persistent MFMA LSTM — proven 210us config, verbatim from R10):
// 64 blocks = 4 row-groups(16 rows) x 16 unit-slices. W_h slice LDS-resident.
// Cross-block h-exchange through the LLC ONLY via relaxed agent u64 ops.
// Counter barrier per step with s_sleep(1). Runs ALONE (R7/R8: overlap cost
// this kernel 1.7x).
// ---------------------------------------------------------------------------
__global__ __launch_bounds__(256) void k_plstm(
    const u16*   __restrict__ Whf,   // [64 ct][8][64][8] h-part frags
    const float* __restrict__ gx,    // [BT][GATES]
    u16*                      Hx,    // [2][BN][HIDN] bf16 exchange (LLC)
    u16*         __restrict__ Hb,    // [BT][HIDN] bf16 output
    u32*                      bar)   // counters (stride 64), zeroed per launch
{
    __shared__ uint4 Wl4[4 * 512];       // 32 KB: [ct][8 q][64 l][8] u16
    __shared__ float gl[4][16][16];      // 4 KB gate exchange

    const int tid  = threadIdx.x;
    const int rg   = blockIdx.x >> 4;    // row group: batch rows rg*16..+15
    const int ns   = blockIdx.x & 15;    // unit slice: units ns*16..+15
    const int u0   = ns * 16;
    const int w    = tid >> 6;           // wave = gate type (i,j,f,o)
    const int lane = tid & 63;
    const int m    = lane & 15, kq = lane >> 4;

    {   // load W_h slice: tiles c = w'*16 + ns, 8 KB contiguous each
        const uint4* src = (const uint4*)Whf;
        #pragma unroll
        for (int i = 0; i < 8; ++i) {
            int e  = tid + i * 256;          // [0, 2048)
            int ct = e >> 9, off = e & 511;  // 512 uint4 per tile
            Wl4[e] = src[(size_t)(ct * 16 + ns) * 512 + off];
        }
    }
    {   // zero gate-exchange so t=0 reads 0 for the h@W_h term
        float* g0 = (float*)gl;
        #pragma unroll
        for (int j = 0; j < 4; ++j) g0[tid * 4 + j] = 0.0f;
    }
    __syncthreads();

    const u16* Wl = (const u16*)Wl4;

    const int r = tid >> 4, u = tid & 15;
    const int b = rg * 16 + r;                       // batch row
    const float* gxp = gx + (size_t)b * TN * GATES + u0 + u;
    u16* hbp = Hb + (size_t)b * TN * HIDN + u0 + u;
    const int hxw = b * HIDN + u0 + u;               // Hx elem offset (in-buf)
    const int aoff = (rg * 16 + m) * HIDN + kq * 8;  // a-frag elem offset

    float cstate = 0.0f;
    float4 gxr;
    gxr.x = gxp[0]; gxr.y = gxp[256]; gxr.z = gxp[512]; gxr.w = gxp[768];

    for (int t = 0; t < TN; ++t) {
        // prefetch next step's x-gates early (hide HBM latency behind MFMA)
        float4 gxn = gxr;
        if (t + 1 < TN) {
            const float* p = gxp + (size_t)(t + 1) * GATES;
            gxn.x = p[0]; gxn.y = p[256]; gxn.z = p[512]; gxn.w = p[768];
        }

        if (t > 0) {
            // a-frags from LLC: relaxed agent u64 atomic loads (sc0 sc1)
            const u64* hsrc = (const u64*)(Hx + (t & 1) * (BN * HIDN) + aoff);
            v4f acc = {0.f, 0.f, 0.f, 0.f};
            #pragma unroll
            for (int q = 0; q < 8; ++q) {
                union { u64 d[2]; v8s v; } av;
                av.d[0] = llc_load(hsrc + q * 8);
                av.d[1] = llc_load(hsrc + q * 8 + 1);
                v8s bf = *(const v8s*)(Wl + ((w * 8 + q) * 64 + lane) * 8);
                acc = __builtin_amdgcn_mfma_f32_16x16x32_bf16(av.v, bf, acc, 0, 0, 0);
            }
            #pragma unroll
            for (int rr = 0; rr < 4; ++rr)   // row = kq*4+rr, col(unit) = m
                gl[w][kq * 4 + rr][m] = acc[rr];
        }
        __syncthreads();

        {   // cell update for (r, u); c stays in a register
            float ai = gl[0][r][u] + gxr.x;
            float aj = gl[1][r][u] + gxr.y;
            float af = gl[2][r][u] + gxr.z;
            float ao = gl[3][r][u] + gxr.w;
            float ig = fast_sigmoid(ai);
            float fg = fast_sigmoid(af + 1.0f);      // forget_bias = 1.0
            float og = fast_sigmoid(ao);
            float jt = fast_tanh(aj);
            cstate = fg * cstate + ig * jt;
            float hn = og * fast_tanh(cstate);
            u32 hv = f2bf(hn);
            hbp[(size_t)t * HIDN] = (u16)hv;

            if (t + 1 < TN) {
                // pack 4 consecutive units (same row, lanes tid..tid+3) into
                // one u64 and publish via relaxed agent atomic store -> LLC
                u32 p1 = __shfl_down(hv, 1);
                u32 p2 = __shfl_down(hv, 2);
                u32 p3 = __shfl_down(hv, 3);
                if ((tid & 3) == 0) {
                    u64 pk = (u64)(hv | (p1 << 16))
                           | ((u64)(p2 | (p3 << 16)) << 32);
                    u64* dst = (u64*)(Hx + (((t & 1) ^ 1) * (BN * HIDN)) + hxw);
                    llc_store(dst, pk);
                }
            }
        }

        if (t + 1 < TN) {
            __syncthreads();   // per-wave vmcnt(0) before s_barrier: all
                               // publish stores have reached the LLC
            if (tid == 0) {
                cnt_add(&bar[rg * 64]);
                u32 tgt = (u32)(t + 1) * 16u;
                while (cnt_read(&bar[rg * 64]) < tgt)
                    __builtin_amdgcn_s_sleep(1);
            }
            __syncthreads();   // broadcast release; also orders next gl writes
        }
        gxr = gxn;
    }
}

// ---------------------------------------------------------------------------
// POST kernel (881 blocks):
//   0..624  : W_dense tile -> Wf (llc_store), bump wfdone
//   625..880: dense — spin wfdone==625, then R10's 4-quarter MFMA sweep
//     (64 rows, register-resident a-frags) + fused target capture (llc_storef
//     tl) + fp32 atomicAdd of S at LLC + per-rg arrival counter; the 4th
//     arriver reads S/tl from LLC and writes the 64 perplexities.
// Wf aliases gx (plstm already consumed gx — POST is a later launch).
// No deadlock: wfrag blocks never wait; dense blocks spin on LLC counter.
// ---------------------------------------------------------------------------
__global__ __launch_bounds__(256, 1) void k_post(
    const float* __restrict__ W_dense,
    const u16*   __restrict__ Hb,    // [BT][HIDN] bf16
    u16*         __restrict__ Wf,    // [625][8][64][8]
    const float* __restrict__ bd,    // [VOCAB]
    const int*   __restrict__ tgt,   // [BT]
    float*                    S,     // [BT] sumexp accumulators (zeroed)
    float*                    tl,    // [BT] target logits
    u32*                      wfdone,
    u32*                      sdone, // [64] per-row-group arrival counters
    float*       __restrict__ out)   // [BT] perplexity
{
    __shared__ u16   lt[HIDN][16];
    __shared__ float Sl[64];
    __shared__ int   tg[64];

    const int bid = blockIdx.x;
    const int tid = threadIdx.x;

    if (bid < NCT) {
        wfrag_dev(W_dense, Wf, VOCABN, bid, tid, lt);
        __syncthreads();                 // drain llc_stores
        if (tid == 0) cnt_add(wfdone);
        return;
    }

    // ---- dense role ----
    const int db  = bid - NCT;                 // 0..255
    const int hv  = db & 3;                    // vocab quarter (XCD-aligned)
    const int rg  = db >> 2;                   // 0..63
    const int r0  = rg * 64;
    const int w   = tid >> 6, lane = tid & 63;
    const int m   = lane & 15, kq = lane >> 4;

    if (tid < 64) { Sl[tid] = 0.0f; tg[tid] = tgt[r0 + tid]; }
    if (tid == 0)
        while (cnt_read(wfdone) < (u32)NCT) __builtin_amdgcn_s_sleep(16);
    __syncthreads();

    v8s a[4][8];
    #pragma unroll
    for (int rt = 0; rt < 4; ++rt) {
        const u16* hrow = Hb + (size_t)(r0 + rt * 16 + m) * HIDN + kq * 8;
        #pragma unroll
        for (int q = 0; q < 8; ++q)
            a[rt][q] = *(const v8s*)(hrow + q * 32);
    }

    float s[4][4] = {{0.f,0.f,0.f,0.f},{0.f,0.f,0.f,0.f},
                     {0.f,0.f,0.f,0.f},{0.f,0.f,0.f,0.f}};
    const int cbeg = (hv * NCT) >> 2;
    const int cend = ((hv + 1) * NCT) >> 2;
    for (int c = cbeg + w; c < cend; c += 4) {
        v4f acc[4] = {{0.f,0.f,0.f,0.f},{0.f,0.f,0.f,0.f},
                      {0.f,0.f,0.f,0.f},{0.f,0.f,0.f,0.f}};
        #pragma unroll
        for (int q = 0; q < 8; ++q) {
            // Wf written via llc_store (no stale L2 copies); plain load reads
            // LLC-fresh and lets the quarter cache in this XCD's L2.
            v8s bq = *(const v8s*)(Wf + (((size_t)c * 8 + q) * 64 + lane) * 8);
            #pragma unroll
            for (int rt = 0; rt < 4; ++rt)
                acc[rt] = __builtin_amdgcn_mfma_f32_16x16x32_bf16(
                              a[rt][q], bq, acc[rt], 0, 0, 0);
        }
        const int col = c * 16 + m;
        const float bv = bd[col];
        #pragma unroll
        for (int rt = 0; rt < 4; ++rt)
            #pragma unroll
            for (int r = 0; r < 4; ++r) {
                float l = acc[rt][r] + bv;
                int row = rt * 16 + kq * 4 + r;       // batch row 0..63
                if (col == tg[row]) llc_storef(&tl[r0 + row], l);
                s[rt][r] += __expf(l);
            }
    }

    #pragma unroll
    for (int rt = 0; rt < 4; ++rt)
        #pragma unroll
        for (int r = 0; r < 4; ++r)
            atomicAdd(&Sl[rt * 16 + kq * 4 + r], s[rt][r]);
    __syncthreads();
    if (tid < 64) atomicAdd(&S[r0 + tid], Sl[tid]);   // device-scope, at LLC
    __syncthreads();   // drain S-adds + tl stores (vmcnt(0) per wave)

    if (tid == 0) Sl[0] = (float)cnt_add(&sdone[rg]); // arrival index 0..3
    __syncthreads();
    if (Sl[0] == 3.0f) {                               // last of 4 quarters
        if (tid < 64) {
            float sum = llc_loadf(&S[r0 + tid]);
            float t   = llc_loadf(&tl[r0 + tid]);
            out[r0 + tid] = __expf(__logf(sum) - t);
        }
    }
}

// ---------------------------------------------------------------------------
extern "C" void kernel_launch(void* const* d_in, const int* in_sizes, int n_in,
                              void* d_out, int out_size, void* d_ws, size_t ws_size,
                              hipStream_t stream) {
    const int*   input   = (const int*)  d_in[0];   // [B,T]
    const int*   targets = (const int*)  d_in[1];   // [B,T]
    const float* E       = (const float*)d_in[2];   // [VOCAB,HID]
    const float* W_lstm  = (const float*)d_in[3];   // [2H,4H]
    const float* b_lstm  = (const float*)d_in[4];   // [4H]
    const float* W_dense = (const float*)d_in[5];   // [HID,VOCAB]
    const float* b_dense = (const float*)d_in[6];   // [VOCAB]
    float* out = (float*)d_out;                     // [B,T] perplexity

    // Workspace (< 19.2 MB; 20 MB proven in earlier rounds):
    //  [0,16M):            gx fp32 [BT][GATES]; Wf (5.12 MB) reuses this
    //                      region in k_post (after plstm consumed gx).
    //  [16M,18M):          Hb bf16 [BT][HIDN]
    //  [18M,+512K):        Whf (h-part frags)
    //  [18.5M,+512K):      Wxf (x-part frags)
    //  [19M,+64K):         Hx bf16 [2][BN][HIDN] exchange
    //  [19M+64K,+16K):     S fp32 [BT]           (zeroed)
    //  [19M+80K,+16K):     tl fp32 [BT]          (zeroed, then overwritten)
    //  [19M+96K,+1K):      bar u32 [4*64]        (zeroed)
    //  [19M+97K,+256B):    wfdone/wxdone/sdone   (zeroed)
    char* ws = (char*)d_ws;
    float* gx     = (float*)ws;
    u16*   Wf     = (u16*)ws;
    u16*   Hb     = (u16*)(ws + ((size_t)16 << 20));
    u16*   Whf    = (u16*)(ws + ((size_t)18 << 20));
    u16*   Wxf    = (u16*)(ws + ((size_t)18 << 20) + ((size_t)512 << 10));
    u16*   Hx     = (u16*)(ws + ((size_t)19 << 20));
    float* S      = (float*)(ws + ((size_t)19 << 20) + ((size_t)64 << 10));
    float* tl     = (float*)(ws + ((size_t)19 << 20) + ((size_t)80 << 10));
    u32*   bar    = (u32*)  (ws + ((size_t)19 << 20) + ((size_t)96 << 10));
    u32*   cnts   = (u32*)  (ws + ((size_t)19 << 20) + ((size_t)97 << 10));
    u32*   wfdone = cnts;            // [0]
    u32*   wxdone = cnts + 1;        // [1]
    u32*   sdone  = cnts + 2;        // [2..65]

    // zero S, tl, bar, counters in one shot (34 KB starting at S)
    hipMemsetAsync(S, 0, (size_t)34 << 10, stream);
    k_pre  <<<384, 256, 0, stream>>>(W_lstm, input, E, b_lstm,
                                     Wxf, Whf, gx, wxdone);
    k_plstm<<<64,  256, 0, stream>>>(Whf, gx, Hx, Hb, bar);
    k_post <<<NCT + 256, 256, 0, stream>>>(W_dense, Hb, Wf, b_dense, targets,
                                           S, tl, wfdone, sdone, out);
}

// Round 12
// 392.543 us; speedup vs baseline: 1.1915x; 1.1915x over previous
//
#include <hip/hip_runtime.h>
#include <math.h>

// Problem constants (reference: VOCAB=10000, HID=256, B=64, T=64)
#define VOCABN 10000
#define HIDN   256
#define GATES  1024   // 4*HID
#define BN     64
#define TN     64
#define BT     4096   // B*T
#define NCT    625    // vocab col-tiles of 16 (10000 = 625*16 exactly)

typedef unsigned int       u32;
typedef unsigned short     u16;
typedef unsigned long long u64;
typedef float v4f __attribute__((ext_vector_type(4)));
typedef short v8s __attribute__((ext_vector_type(8)));

__device__ __forceinline__ float bf2f(u16 u) {
    return __uint_as_float(((u32)u) << 16);
}
__device__ __forceinline__ u16 f2bf(float f) {          // round-to-nearest-even
    u32 u = __float_as_uint(f);
    u += 0x7FFFu + ((u >> 16) & 1u);
    return (u16)(u >> 16);
}
__device__ __forceinline__ float fast_sigmoid(float x) {
    return 1.0f / (1.0f + __expf(-x));
}
__device__ __forceinline__ float fast_tanh(float x) {
    float e = __expf(-2.0f * fabsf(x));
    float t = (1.0f - e) / (1.0f + e);
    return copysignf(t, x);
}
__device__ __forceinline__ u64 llc_load(const u64* p) {
    return __hip_atomic_load(p, __ATOMIC_RELAXED, __HIP_MEMORY_SCOPE_AGENT);
}
__device__ __forceinline__ void llc_store(u64* p, u64 v) {
    __hip_atomic_store(p, v, __ATOMIC_RELAXED, __HIP_MEMORY_SCOPE_AGENT);
}
__device__ __forceinline__ u32 flag_read(const u32* p) {
    return __hip_atomic_load(p, __ATOMIC_RELAXED, __HIP_MEMORY_SCOPE_AGENT);
}
__device__ __forceinline__ void flag_write(u32* p, u32 v) {
    __hip_atomic_store(p, v, __ATOMIC_RELAXED, __HIP_MEMORY_SCOPE_AGENT);
}

// ---------------------------------------------------------------------------
// fp32 [HIDN][ncols] tile c -> bf16 MFMA B-fragment layout [c][8 q][64 l][8].
// Fragment (c,q), lane l holds B[k = q*32 + (l>>4)*8 + j][n = c*16 + (l&15)].
// Plain uint4 stores (writer-L2 cached; cross-kernel visibility via the
// end-of-dispatch flush — consumers are always later launches).
// ---------------------------------------------------------------------------
__device__ __forceinline__ void wfrag_dev(
    const float* __restrict__ src, u16* __restrict__ dst, int ncols, int c,
    int t, u16 lt[HIDN][16])
{
    const float* s = src + (size_t)t * ncols + c * 16;
    #pragma unroll
    for (int j4 = 0; j4 < 4; ++j4) {
        float4 v = *(const float4*)(s + j4 * 4);
        lt[t][j4*4+0] = f2bf(v.x);
        lt[t][j4*4+1] = f2bf(v.y);
        lt[t][j4*4+2] = f2bf(v.z);
        lt[t][j4*4+3] = f2bf(v.w);
    }
    __syncthreads();
    #pragma unroll
    for (int h = 0; h < 2; ++h) {
        int f = t + h * 256;             // frag id = q*64 + l
        int q = f >> 6, l = f & 63;
        int m = l & 15, kb = q * 32 + ((l >> 4) & 3) * 8;
        u32 w[4];
        #pragma unroll
        for (int j = 0; j < 4; ++j)
            w[j] = (u32)lt[kb + 2*j][m] | ((u32)lt[kb + 2*j + 1][m] << 16);
        *(uint4*)(dst + (((size_t)c * 8 + q) * 64 + l) * 8) =
            make_uint4(w[0], w[1], w[2], w[3]);
    }
}

// ---------------------------------------------------------------------------
// wfrag for both W_lstm halves in one launch (128 blocks, data-parallel).
// ---------------------------------------------------------------------------
__global__ __launch_bounds__(256) void k_wfrag2(
    const float* __restrict__ W_lstm,
    u16* __restrict__ Wxf, u16* __restrict__ Whf)
{
    __shared__ u16 lt[HIDN][16];
    const int bid = blockIdx.x;
    if (bid < 64)
        wfrag_dev(W_lstm, Wxf, GATES, bid, threadIdx.x, lt);
    else
        wfrag_dev(W_lstm + (size_t)HIDN * GATES, Whf, GATES, bid - 64,
                  threadIdx.x, lt);
}

// ---------------------------------------------------------------------------
// wfrag for W_dense (625 blocks) — runs AFTER plstm, Wf aliases gx.
// ---------------------------------------------------------------------------
__global__ __launch_bounds__(256) void k_wfrag(
    const float* __restrict__ src,   // [HIDN][ncols]
    u16*         __restrict__ dst,   // [nct][8][64][8]
    int ncols)
{
    __shared__ u16 lt[HIDN][16];
    wfrag_dev(src, dst, ncols, blockIdx.x, threadIdx.x, lt);
}

// ---------------------------------------------------------------------------
// Kernel 1 (MFMA): gates_x = E[idx] @ W_x + b_lstm. 256 blocks x 16 rows.
// ---------------------------------------------------------------------------
__global__ __launch_bounds__(256) void k_xgates(
    const int*   __restrict__ idx,   // [BT]
    const float* __restrict__ E,     // [VOCAB][HIDN]
    const u16*   __restrict__ Wxf,   // [64][8][64][8]
    const float* __restrict__ bl,    // [GATES]
    float*       __restrict__ gx)    // [BT][GATES]
{
    const int r0   = blockIdx.x * 16;
    const int tid  = threadIdx.x;
    const int w    = tid >> 6, lane = tid & 63;
    const int m    = lane & 15, quad = lane >> 4;

    v8s a[8];
    {
        const float* e = E + (size_t)idx[r0 + m] * HIDN + quad * 8;
        #pragma unroll
        for (int q = 0; q < 8; ++q) {
            float4 x0 = *(const float4*)(e + q * 32);
            float4 x1 = *(const float4*)(e + q * 32 + 4);
            uint4 t4 = make_uint4(
                (u32)f2bf(x0.x) | ((u32)f2bf(x0.y) << 16),
                (u32)f2bf(x0.z) | ((u32)f2bf(x0.w) << 16),
                (u32)f2bf(x1.x) | ((u32)f2bf(x1.y) << 16),
                (u32)f2bf(x1.z) | ((u32)f2bf(x1.w) << 16));
            a[q] = *(v8s*)&t4;
        }
    }

    for (int c = w; c < GATES / 16; c += 4) {
        v4f acc = {0.f, 0.f, 0.f, 0.f};
        #pragma unroll
        for (int q = 0; q < 8; ++q) {
            v8s b = *(const v8s*)(Wxf + (((size_t)c * 8 + q) * 64 + lane) * 8);
            acc = __builtin_amdgcn_mfma_f32_16x16x32_bf16(a[q], b, acc, 0, 0, 0);
        }
        const int col = c * 16 + m;
        const float bv = bl[col];
        #pragma unroll
        for (int r = 0; r < 4; ++r)   // D: col=lane&15, row=quad*4+r (m89/m91)
            gx[(size_t)(r0 + quad * 4 + r) * GATES + col] = acc[r] + bv;
    }
}

// ---------------------------------------------------------------------------
// Kernel 2 (persistent MFMA LSTM — R10's proven structure; ONE change: the
// per-step barrier uses a 16-entry FLAG ARRAY (64B-strided) instead of a
// single atomicAdd counter. Producers' flag stores are independent LLC
// addresses (parallel, no RMW serialization); lanes 0-15 of wave 0 poll all
// 16 flags with one memory instruction per iteration. Runs ALONE (R7/R8:
// co-running dense cost this kernel 1.7x).
// ---------------------------------------------------------------------------
__global__ __launch_bounds__(256) void k_plstm(
    const u16*   __restrict__ Whf,   // [64 ct][8][64][8] h-part frags
    const float* __restrict__ gx,    // [BT][GATES]
    u16*                      Hx,    // [2][BN][HIDN] bf16 exchange (LLC)
    u16*         __restrict__ Hb,    // [BT][HIDN] bf16 output
    u32*                      bar)   // flags[4 rg][16 ns], 64B-strided, zeroed
{
    __shared__ uint4 Wl4[4 * 512];       // 32 KB: [ct][8 q][64 l][8] u16
    __shared__ float gl[4][16][16];      // 4 KB gate exchange

    const int tid  = threadIdx.x;
    const int rg   = blockIdx.x >> 4;    // row group: batch rows rg*16..+15
    const int ns   = blockIdx.x & 15;    // unit slice: units ns*16..+15
    const int u0   = ns * 16;
    const int w    = tid >> 6;           // wave = gate type (i,j,f,o)
    const int lane = tid & 63;
    const int m    = lane & 15, kq = lane >> 4;

    {   // load W_h slice: tiles c = w'*16 + ns, 8 KB contiguous each
        const uint4* src = (const uint4*)Whf;
        #pragma unroll
        for (int i = 0; i < 8; ++i) {
            int e  = tid + i * 256;          // [0, 2048)
            int ct = e >> 9, off = e & 511;  // 512 uint4 per tile
            Wl4[e] = src[(size_t)(ct * 16 + ns) * 512 + off];
        }
    }
    {   // zero gate-exchange so t=0 reads 0 for the h@W_h term
        float* g0 = (float*)gl;
        #pragma unroll
        for (int j = 0; j < 4; ++j) g0[tid * 4 + j] = 0.0f;
    }
    __syncthreads();

    const u16* Wl = (const u16*)Wl4;

    const int r = tid >> 4, u = tid & 15;
    const int b = rg * 16 + r;                       // batch row
    const float* gxp = gx + (size_t)b * TN * GATES + u0 + u;
    u16* hbp = Hb + (size_t)b * TN * HIDN + u0 + u;
    const int hxw = b * HIDN + u0 + u;               // Hx elem offset (in-buf)
    const int aoff = (rg * 16 + m) * HIDN + kq * 8;  // a-frag elem offset

    u32* myflag   = bar + (rg * 16 + ns) * 16;       // 64B-strided flags
    u32* pollflag = bar + (rg * 16 + (tid & 15)) * 16;

    float cstate = 0.0f;
    float4 gxr;
    gxr.x = gxp[0]; gxr.y = gxp[256]; gxr.z = gxp[512]; gxr.w = gxp[768];

    for (int t = 0; t < TN; ++t) {
        // prefetch next step's x-gates early (hide HBM latency behind MFMA)
        float4 gxn = gxr;
        if (t + 1 < TN) {
            const float* p = gxp + (size_t)(t + 1) * GATES;
            gxn.x = p[0]; gxn.y = p[256]; gxn.z = p[512]; gxn.w = p[768];
        }

        if (t > 0) {
            // a-frags from LLC: relaxed agent u64 atomic loads (sc0 sc1)
            const u64* hsrc = (const u64*)(Hx + (t & 1) * (BN * HIDN) + aoff);
            v4f acc = {0.f, 0.f, 0.f, 0.f};
            #pragma unroll
            for (int q = 0; q < 8; ++q) {
                union { u64 d[2]; v8s v; } av;
                av.d[0] = llc_load(hsrc + q * 8);
                av.d[1] = llc_load(hsrc + q * 8 + 1);
                v8s bf = *(const v8s*)(Wl + ((w * 8 + q) * 64 + lane) * 8);
                acc = __builtin_amdgcn_mfma_f32_16x16x32_bf16(av.v, bf, acc, 0, 0, 0);
            }
            #pragma unroll
            for (int rr = 0; rr < 4; ++rr)   // row = kq*4+rr, col(unit) = m
                gl[w][kq * 4 + rr][m] = acc[rr];
        }
        __syncthreads();

        {   // cell update for (r, u); c stays in a register
            float ai = gl[0][r][u] + gxr.x;
            float aj = gl[1][r][u] + gxr.y;
            float af = gl[2][r][u] + gxr.z;
            float ao = gl[3][r][u] + gxr.w;
            float ig = fast_sigmoid(ai);
            float fg = fast_sigmoid(af + 1.0f);      // forget_bias = 1.0
            float og = fast_sigmoid(ao);
            float jt = fast_tanh(aj);
            cstate = fg * cstate + ig * jt;
            float hn = og * fast_tanh(cstate);
            u32 hv = f2bf(hn);
            hbp[(size_t)t * HIDN] = (u16)hv;

            if (t + 1 < TN) {
                // pack 4 consecutive units (same row, lanes tid..tid+3) into
                // one u64 and publish via relaxed agent atomic store -> LLC
                u32 p1 = __shfl_down(hv, 1);
                u32 p2 = __shfl_down(hv, 2);
                u32 p3 = __shfl_down(hv, 3);
                if ((tid & 3) == 0) {
                    u64 pk = (u64)(hv | (p1 << 16))
                           | ((u64)(p2 | (p3 << 16)) << 32);
                    u64* dst = (u64*)(Hx + (((t & 1) ^ 1) * (BN * HIDN)) + hxw);
                    llc_store(dst, pk);
                }
            }
        }

        if (t + 1 < TN) {
            __syncthreads();   // per-wave vmcnt(0) before s_barrier: all
                               // publish stores have reached the LLC
            if (tid == 0) flag_write(myflag, (u32)(t + 1));
            if (tid < 16) {    // 16 lanes poll 16 flags in parallel
                while (flag_read(pollflag) < (u32)(t + 1))
                    __builtin_amdgcn_s_sleep(1);
            }
            __syncthreads();   // broadcast release; also orders next gl writes
        }
        gxr = gxn;
    }
}

// ---------------------------------------------------------------------------
// Kernel 3 (MFMA dense, 4-way vocab split — verbatim from R10's win):
// 256 blocks = 64 row-groups(64 rows, 4 register-resident a-frag row-tiles)
// x 4 vocab quarters (1.28 MB Wf each, fits an XCD L2; hv=bid&3 aligns
// quarters to XCDs under round-robin %8 — perf-only assumption, G16-safe).
// ---------------------------------------------------------------------------
__global__ __launch_bounds__(256, 1) void k_dense(
    const u16*   __restrict__ Hb,    // [BT][HIDN] bf16
    const u16*   __restrict__ Wf,    // [625][8][64][8]
    const float* __restrict__ bd,    // [VOCAB]
    float*       __restrict__ S)     // [4][BT] partial sumexp
{
    __shared__ float Sl[64];
    const int bid = blockIdx.x;
    const int hv  = bid & 3;                    // vocab quarter (XCD-aligned)
    const int rg  = bid >> 2;                   // 0..63
    const int r0  = rg * 64;
    const int tid = threadIdx.x;
    const int w   = tid >> 6, lane = tid & 63;
    const int m   = lane & 15, kq = lane >> 4;

    if (tid < 64) Sl[tid] = 0.0f;

    v8s a[4][8];
    #pragma unroll
    for (int rt = 0; rt < 4; ++rt) {
        const u16* hrow = Hb + (size_t)(r0 + rt * 16 + m) * HIDN + kq * 8;
        #pragma unroll
        for (int q = 0; q < 8; ++q)
            a[rt][q] = *(const v8s*)(hrow + q * 32);
    }
    __syncthreads();

    float s[4][4] = {{0.f,0.f,0.f,0.f},{0.f,0.f,0.f,0.f},
                     {0.f,0.f,0.f,0.f},{0.f,0.f,0.f,0.f}};
    const int cbeg = (hv * NCT) >> 2;
    const int cend = ((hv + 1) * NCT) >> 2;
    for (int c = cbeg + w; c < cend; c += 4) {
        v4f acc[4] = {{0.f,0.f,0.f,0.f},{0.f,0.f,0.f,0.f},
                      {0.f,0.f,0.f,0.f},{0.f,0.f,0.f,0.f}};
        #pragma unroll
        for (int q = 0; q < 8; ++q) {
            v8s bq = *(const v8s*)(Wf + (((size_t)c * 8 + q) * 64 + lane) * 8);
            #pragma unroll
            for (int rt = 0; rt < 4; ++rt)
                acc[rt] = __builtin_amdgcn_mfma_f32_16x16x32_bf16(
                              a[rt][q], bq, acc[rt], 0, 0, 0);
        }
        const float bv = bd[c * 16 + m];
        #pragma unroll
        for (int rt = 0; rt < 4; ++rt)
            #pragma unroll
            for (int r = 0; r < 4; ++r)
                s[rt][r] += __expf(acc[rt][r] + bv);
    }

    #pragma unroll
    for (int rt = 0; rt < 4; ++rt)
        #pragma unroll
        for (int r = 0; r < 4; ++r)
            atomicAdd(&Sl[rt * 16 + kq * 4 + r], s[rt][r]);
    __syncthreads();
    if (tid < 64) S[(size_t)hv * BT + r0 + tid] = Sl[tid];
}

// ---------------------------------------------------------------------------
// Kernel 4 (target + final fused): per row, dot h with the target's W column
// (direct from bf16 frags, 32 thr/row), then ppl = exp(log(sum S) - logit).
// S is complete (k_dense retired before this launch).
// ---------------------------------------------------------------------------
__global__ __launch_bounds__(256) void k_target(
    const u16*   __restrict__ Hb,
    const u16*   __restrict__ Wf,
    const float* __restrict__ bd,
    const int*   __restrict__ tgt,
    const float* __restrict__ S,     // [4][BT]
    float*       __restrict__ out)   // [BT]
{
    const int tid = threadIdx.x;
    const int row = blockIdx.x * 8 + (tid >> 5);
    const int t   = tid & 31;
    const int q   = t >> 2, lq = t & 3;
    const int v   = tgt[row];
    const int c   = v >> 4, vm = v & 15;
    const int kb  = q * 32 + lq * 8;

    v8s h  = *(const v8s*)(Hb + (size_t)row * HIDN + kb);
    v8s wv = *(const v8s*)(Wf + (((size_t)c * 8 + q) * 64 + lq * 16 + vm) * 8);
    float acc = 0.0f;
    #pragma unroll
    for (int j = 0; j < 8; ++j)
        acc = fmaf(bf2f((u16)h[j]), bf2f((u16)wv[j]), acc);
    #pragma unroll
    for (int off = 16; off >= 1; off >>= 1)
        acc += __shfl_down(acc, off, 32);
    if (t == 0) {
        float tlv = acc + bd[v];
        float sum = S[row] + S[BT + row] + S[2 * BT + row] + S[3 * BT + row];
        out[row] = __expf(__logf(sum) - tlv);
    }
}

// ---------------------------------------------------------------------------
extern "C" void kernel_launch(void* const* d_in, const int* in_sizes, int n_in,
                              void* d_out, int out_size, void* d_ws, size_t ws_size,
                              hipStream_t stream) {
    const int*   input   = (const int*)  d_in[0];   // [B,T]
    const int*   targets = (const int*)  d_in[1];   // [B,T]
    const float* E       = (const float*)d_in[2];   // [VOCAB,HID]
    const float* W_lstm  = (const float*)d_in[3];   // [2H,4H]
    const float* b_lstm  = (const float*)d_in[4];   // [4H]
    const float* W_dense = (const float*)d_in[5];   // [HID,VOCAB]
    const float* b_dense = (const float*)d_in[6];   // [VOCAB]
    float* out = (float*)d_out;                     // [B,T] perplexity

    // Workspace (< 19.3 MB; 20 MB proven in earlier rounds):
    //  [0,16M):            gx fp32 [BT][GATES]; Wf (5.12 MB) reuses this
    //                      region after k_plstm consumes gx (stream-ordered).
    //  [16M,18M):          Hb bf16 [BT][HIDN]
    //  [18M,+512K):        Whf (h-part frags)
    //  [18.5M,+512K):      Wxf (x-part frags)
    //  [19M,+64K):         Hx bf16 [2][BN][HIDN] exchange
    //  [19M+64K,+64K):     S fp32 [4][BT]
    //  [19M+128K,+4K):     bar u32 flags [4 rg][16 ns] 64B-strided (zeroed)
    char* ws = (char*)d_ws;
    float* gx  = (float*)ws;
    u16*   Wf  = (u16*)ws;
    u16*   Hb  = (u16*)(ws + ((size_t)16 << 20));
    u16*   Whf = (u16*)(ws + ((size_t)18 << 20));
    u16*   Wxf = (u16*)(ws + ((size_t)18 << 20) + ((size_t)512 << 10));
    u16*   Hx  = (u16*)(ws + ((size_t)19 << 20));
    float* S   = (float*)(ws + ((size_t)19 << 20) + ((size_t)64 << 10));
    u32*   bar = (u32*)  (ws + ((size_t)19 << 20) + ((size_t)128 << 10));

    hipMemsetAsync(bar, 0, 4096, stream);
    k_wfrag2<<<128,      256, 0, stream>>>(W_lstm, Wxf, Whf);
    k_xgates<<<BT / 16,  256, 0, stream>>>(input, E, Wxf, b_lstm, gx);
    k_plstm <<<64,       256, 0, stream>>>(Whf, gx, Hx, Hb, bar);
    k_wfrag <<<NCT,      256, 0, stream>>>(W_dense, Wf, VOCABN);   // reuses gx
    k_dense <<<256,      256, 0, stream>>>(Hb, Wf, b_dense, S);
    k_target<<<BT / 8,   256, 0, stream>>>(Hb, Wf, b_dense, targets, S, out);
}

// Round 14
// 361.019 us; speedup vs baseline: 1.2956x; 1.0873x over previous
//
#include <hip/hip_runtime.h>
#include <math.h>

// Problem constants (reference: VOCAB=10000, HID=256, B=64, T=64)
#define VOCABN 10000
#define HIDN   256
#define GATES  1024   // 4*HID
#define BN     64
#define TN     64
#define BT     4096   // B*T
#define NCT    625    // vocab col-tiles of 16 (10000 = 625*16 exactly)

typedef unsigned int       u32;
typedef unsigned short     u16;
typedef unsigned long long u64;
typedef float v4f __attribute__((ext_vector_type(4)));
typedef short v8s __attribute__((ext_vector_type(8)));

__device__ __forceinline__ float bf2f(u16 u) {
    return __uint_as_float(((u32)u) << 16);
}
__device__ __forceinline__ u16 f2bf(float f) {          // round-to-nearest-even
    u32 u = __float_as_uint(f);
    u += 0x7FFFu + ((u >> 16) & 1u);
    return (u16)(u >> 16);
}
__device__ __forceinline__ float fast_sigmoid(float x) {
    return 1.0f / (1.0f + __expf(-x));
}
__device__ __forceinline__ float fast_tanh(float x) {
    float e = __expf(-2.0f * fabsf(x));
    float t = (1.0f - e) / (1.0f + e);
    return copysignf(t, x);
}
__device__ __forceinline__ u64 llc_load(const u64* p) {
    return __hip_atomic_load(p, __ATOMIC_RELAXED, __HIP_MEMORY_SCOPE_AGENT);
}
__device__ __forceinline__ void llc_store(u64* p, u64 v) {
    __hip_atomic_store(p, v, __ATOMIC_RELAXED, __HIP_MEMORY_SCOPE_AGENT);
}
__device__ __forceinline__ u32 cnt_add(u32* p) {
    return __hip_atomic_fetch_add(p, 1u, __ATOMIC_RELAXED,
                                  __HIP_MEMORY_SCOPE_AGENT);
}
__device__ __forceinline__ u32 cnt_read(u32* p) {
    return __hip_atomic_load(p, __ATOMIC_RELAXED, __HIP_MEMORY_SCOPE_AGENT);
}

// ---------------------------------------------------------------------------
// fp32 [HIDN][ncols] tile c -> bf16 MFMA B-fragment layout [c][8 q][64 l][8].
// Fragment (c,q), lane l holds B[k = q*32 + (l>>4)*8 + j][n = c*16 + (l&15)].
// Plain uint4 stores (writer-L2 cached; cross-kernel visibility via the
// end-of-dispatch flush — consumers are always later launches).
// ---------------------------------------------------------------------------
__device__ __forceinline__ void wfrag_dev(
    const float* __restrict__ src, u16* __restrict__ dst, int ncols, int c,
    int t, u16 lt[HIDN][16])
{
    const float* s = src + (size_t)t * ncols + c * 16;
    #pragma unroll
    for (int j4 = 0; j4 < 4; ++j4) {
        float4 v = *(const float4*)(s + j4 * 4);
        lt[t][j4*4+0] = f2bf(v.x);
        lt[t][j4*4+1] = f2bf(v.y);
        lt[t][j4*4+2] = f2bf(v.z);
        lt[t][j4*4+3] = f2bf(v.w);
    }
    __syncthreads();
    #pragma unroll
    for (int h = 0; h < 2; ++h) {
        int f = t + h * 256;             // frag id = q*64 + l
        int q = f >> 6, l = f & 63;
        int m = l & 15, kb = q * 32 + ((l >> 4) & 3) * 8;
        u32 w[4];
        #pragma unroll
        for (int j = 0; j < 4; ++j)
            w[j] = (u32)lt[kb + 2*j][m] | ((u32)lt[kb + 2*j + 1][m] << 16);
        *(uint4*)(dst + (((size_t)c * 8 + q) * 64 + l) * 8) =
            make_uint4(w[0], w[1], w[2], w[3]);
    }
}

// ---------------------------------------------------------------------------
// wfrag for both W_lstm halves in one launch (128 blocks). Block 0 also
// zeroes the plstm barrier array (plain stores; the end-of-dispatch flush
// makes them visible to plstm's LLC atomics — same mechanism every
// cross-kernel buffer here already relies on). Replaces the memset node.
// ---------------------------------------------------------------------------
__global__ __launch_bounds__(256) void k_wfrag2(
    const float* __restrict__ W_lstm,
    u16* __restrict__ Wxf, u16* __restrict__ Whf,
    u32* __restrict__ bar)           // [256] u32 (4 rg counters, 64-strided)
{
    __shared__ u16 lt[HIDN][16];
    const int bid = blockIdx.x;
    if (bid == 0) bar[threadIdx.x] = 0u;
    if (bid < 64)
        wfrag_dev(W_lstm, Wxf, GATES, bid, threadIdx.x, lt);
    else
        wfrag_dev(W_lstm + (size_t)HIDN * GATES, Whf, GATES, bid - 64,
                  threadIdx.x, lt);
}

// ---------------------------------------------------------------------------
// wfrag for W_dense (625 blocks) — runs AFTER plstm, Wf aliases gx.
// ---------------------------------------------------------------------------
__global__ __launch_bounds__(256) void k_wfrag(
    const float* __restrict__ src,   // [HIDN][ncols]
    u16*         __restrict__ dst,   // [nct][8][64][8]
    int ncols)
{
    __shared__ u16 lt[HIDN][16];
    wfrag_dev(src, dst, ncols, blockIdx.x, threadIdx.x, lt);
}

// ---------------------------------------------------------------------------
// Kernel 1 (MFMA): gates_x = E[idx] @ W_x + b_lstm. 256 blocks x 16 rows.
// gx stays fp32: bf16 gx cost plstm +14us (R9 vs R10 A/B).
// ---------------------------------------------------------------------------
__global__ __launch_bounds__(256) void k_xgates(
    const int*   __restrict__ idx,   // [BT]
    const float* __restrict__ E,     // [VOCAB][HIDN]
    const u16*   __restrict__ Wxf,   // [64][8][64][8]
    const float* __restrict__ bl,    // [GATES]
    float*       __restrict__ gx)    // [BT][GATES]
{
    const int r0   = blockIdx.x * 16;
    const int tid  = threadIdx.x;
    const int w    = tid >> 6, lane = tid & 63;
    const int m    = lane & 15, quad = lane >> 4;

    v8s a[8];
    {
        const float* e = E + (size_t)idx[r0 + m] * HIDN + quad * 8;
        #pragma unroll
        for (int q = 0; q < 8; ++q) {
            float4 x0 = *(const float4*)(e + q * 32);
            float4 x1 = *(const float4*)(e + q * 32 + 4);
            uint4 t4 = make_uint4(
                (u32)f2bf(x0.x) | ((u32)f2bf(x0.y) << 16),
                (u32)f2bf(x0.z) | ((u32)f2bf(x0.w) << 16),
                (u32)f2bf(x1.x) | ((u32)f2bf(x1.y) << 16),
                (u32)f2bf(x1.z) | ((u32)f2bf(x1.w) << 16));
            a[q] = *(v8s*)&t4;
        }
    }

    for (int c = w; c < GATES / 16; c += 4) {
        v4f acc = {0.f, 0.f, 0.f, 0.f};
        #pragma unroll
        for (int q = 0; q < 8; ++q) {
            v8s b = *(const v8s*)(Wxf + (((size_t)c * 8 + q) * 64 + lane) * 8);
            acc = __builtin_amdgcn_mfma_f32_16x16x32_bf16(a[q], b, acc, 0, 0, 0);
        }
        const int col = c * 16 + m;
        const float bv = bl[col];
        #pragma unroll
        for (int r = 0; r < 4; ++r)   // D: col=lane&15, row=quad*4+r (m89/m91)
            gx[(size_t)(r0 + quad * 4 + r) * GATES + col] = acc[r] + bv;
    }
}

// ---------------------------------------------------------------------------
// Kernel 2 (persistent MFMA LSTM — R10's proven 209us config VERBATIM,
// counter barrier restored: flag-array barrier was +11us, R12 A/B):
// 64 blocks = 4 row-groups(16 rows) x 16 unit-slices. W_h slice LDS-resident.
// Cross-block h-exchange through the LLC ONLY via relaxed agent u64 ops.
// Runs ALONE (R7/R8: co-running dense cost this kernel 1.7x).
// ---------------------------------------------------------------------------
__global__ __launch_bounds__(256) void k_plstm(
    const u16*   __restrict__ Whf,   // [64 ct][8][64][8] h-part frags
    const float* __restrict__ gx,    // [BT][GATES]
    u16*                      Hx,    // [2][BN][HIDN] bf16 exchange (LLC)
    u16*         __restrict__ Hb,    // [BT][HIDN] bf16 output
    u32*                      bar)   // counters (stride 64), zeroed by wfrag2
{
    __shared__ uint4 Wl4[4 * 512];       // 32 KB: [ct][8 q][64 l][8] u16
    __shared__ float gl[4][16][16];      // 4 KB gate exchange

    const int tid  = threadIdx.x;
    const int rg   = blockIdx.x >> 4;    // row group: batch rows rg*16..+15
    const int ns   = blockIdx.x & 15;    // unit slice: units ns*16..+15
    const int u0   = ns * 16;
    const int w    = tid >> 6;           // wave = gate type (i,j,f,o)
    const int lane = tid & 63;
    const int m    = lane & 15, kq = lane >> 4;

    {   // load W_h slice: tiles c = w'*16 + ns, 8 KB contiguous each
        const uint4* src = (const uint4*)Whf;
        #pragma unroll
        for (int i = 0; i < 8; ++i) {
            int e  = tid + i * 256;          // [0, 2048)
            int ct = e >> 9, off = e & 511;  // 512 uint4 per tile
            Wl4[e] = src[(size_t)(ct * 16 + ns) * 512 + off];
        }
    }
    {   // zero gate-exchange so t=0 reads 0 for the h@W_h term
        float* g0 = (float*)gl;
        #pragma unroll
        for (int j = 0; j < 4; ++j) g0[tid * 4 + j] = 0.0f;
    }
    __syncthreads();

    const u16* Wl = (const u16*)Wl4;

    const int r = tid >> 4, u = tid & 15;
    const int b = rg * 16 + r;                       // batch row
    const float* gxp = gx + (size_t)b * TN * GATES + u0 + u;
    u16* hbp = Hb + (size_t)b * TN * HIDN + u0 + u;
    const int hxw = b * HIDN + u0 + u;               // Hx elem offset (in-buf)
    const int aoff = (rg * 16 + m) * HIDN + kq * 8;  // a-frag elem offset

    float cstate = 0.0f;
    float4 gxr;
    gxr.x = gxp[0]; gxr.y = gxp[256]; gxr.z = gxp[512]; gxr.w = gxp[768];

    for (int t = 0; t < TN; ++t) {
        // prefetch next step's x-gates early (hide HBM latency behind MFMA)
        float4 gxn = gxr;
        if (t + 1 < TN) {
            const float* p = gxp + (size_t)(t + 1) * GATES;
            gxn.x = p[0]; gxn.y = p[256]; gxn.z = p[512]; gxn.w = p[768];
        }

        if (t > 0) {
            // a-frags from LLC: relaxed agent u64 atomic loads (sc0 sc1)
            const u64* hsrc = (const u64*)(Hx + (t & 1) * (BN * HIDN) + aoff);
            v4f acc = {0.f, 0.f, 0.f, 0.f};
            #pragma unroll
            for (int q = 0; q < 8; ++q) {
                union { u64 d[2]; v8s v; } av;
                av.d[0] = llc_load(hsrc + q * 8);
                av.d[1] = llc_load(hsrc + q * 8 + 1);
                v8s bf = *(const v8s*)(Wl + ((w * 8 + q) * 64 + lane) * 8);
                acc = __builtin_amdgcn_mfma_f32_16x16x32_bf16(av.v, bf, acc, 0, 0, 0);
            }
            #pragma unroll
            for (int rr = 0; rr < 4; ++rr)   // row = kq*4+rr, col(unit) = m
                gl[w][kq * 4 + rr][m] = acc[rr];
        }
        __syncthreads();

        {   // cell update for (r, u); c stays in a register
            float ai = gl[0][r][u] + gxr.x;
            float aj = gl[1][r][u] + gxr.y;
            float af = gl[2][r][u] + gxr.z;
            float ao = gl[3][r][u] + gxr.w;
            float ig = fast_sigmoid(ai);
            float fg = fast_sigmoid(af + 1.0f);      // forget_bias = 1.0
            float og = fast_sigmoid(ao);
            float jt = fast_tanh(aj);
            cstate = fg * cstate + ig * jt;
            float hn = og * fast_tanh(cstate);
            u32 hv = f2bf(hn);
            hbp[(size_t)t * HIDN] = (u16)hv;

            if (t + 1 < TN) {
                // pack 4 consecutive units (same row, lanes tid..tid+3) into
                // one u64 and publish via relaxed agent atomic store -> LLC
                u32 p1 = __shfl_down(hv, 1);
                u32 p2 = __shfl_down(hv, 2);
                u32 p3 = __shfl_down(hv, 3);
                if ((tid & 3) == 0) {
                    u64 pk = (u64)(hv | (p1 << 16))
                           | ((u64)(p2 | (p3 << 16)) << 32);
                    u64* dst = (u64*)(Hx + (((t & 1) ^ 1) * (BN * HIDN)) + hxw);
                    llc_store(dst, pk);
                }
            }
        }

        if (t + 1 < TN) {
            __syncthreads();   // per-wave vmcnt(0) before s_barrier: all
                               // publish stores have reached the LLC
            if (tid == 0) {
                cnt_add(&bar[rg * 64]);
                u32 tgt = (u32)(t + 1) * 16u;
                while (cnt_read(&bar[rg * 64]) < tgt)
                    __builtin_amdgcn_s_sleep(1);
            }
            __syncthreads();   // broadcast release; also orders next gl writes
        }
        gxr = gxn;
    }
}

// ---------------------------------------------------------------------------
// Kernel 3 (MFMA dense, 8-way vocab split): 512 blocks = 64 row-groups
// (64 rows, 4 register-resident a-frag row-tiles) x 8 vocab eighths
// (~78 tiles = 640 KB Wf each). hv = bid & 7: under round-robin %8 each
// XCD's 64 blocks share ONE eighth that stays L2-resident — ~2x less Wf
// cache traffic than the R10 quarter split (perf-only assumption, G16-safe).
// No running max: |logit| small, exp never overflows fp32.
// ---------------------------------------------------------------------------
__global__ __launch_bounds__(256, 1) void k_dense(
    const u16*   __restrict__ Hb,    // [BT][HIDN] bf16
    const u16*   __restrict__ Wf,    // [625][8][64][8]
    const float* __restrict__ bd,    // [VOCAB]
    float*       __restrict__ S)     // [8][BT] partial sumexp
{
    __shared__ float Sl[64];
    const int bid = blockIdx.x;
    const int hv  = bid & 7;                    // vocab eighth (XCD-aligned)
    const int rg  = bid >> 3;                   // 0..63
    const int r0  = rg * 64;
    const int tid = threadIdx.x;
    const int w   = tid >> 6, lane = tid & 63;
    const int m   = lane & 15, kq = lane >> 4;

    if (tid < 64) Sl[tid] = 0.0f;

    v8s a[4][8];
    #pragma unroll
    for (int rt = 0; rt < 4; ++rt) {
        const u16* hrow = Hb + (size_t)(r0 + rt * 16 + m) * HIDN + kq * 8;
        #pragma unroll
        for (int q = 0; q < 8; ++q)
            a[rt][q] = *(const v8s*)(hrow + q * 32);
    }
    __syncthreads();

    float s[4][4] = {{0.f,0.f,0.f,0.f},{0.f,0.f,0.f,0.f},
                     {0.f,0.f,0.f,0.f},{0.f,0.f,0.f,0.f}};
    const int cbeg = (hv * NCT) >> 3;
    const int cend = ((hv + 1) * NCT) >> 3;
    for (int c = cbeg + w; c < cend; c += 4) {
        v4f acc[4] = {{0.f,0.f,0.f,0.f},{0.f,0.f,0.f,0.f},
                      {0.f,0.f,0.f,0.f},{0.f,0.f,0.f,0.f}};
        #pragma unroll
        for (int q = 0; q < 8; ++q) {
            v8s bq = *(const v8s*)(Wf + (((size_t)c * 8 + q) * 64 + lane) * 8);
            #pragma unroll
            for (int rt = 0; rt < 4; ++rt)
                acc[rt] = __builtin_amdgcn_mfma_f32_16x16x32_bf16(
                              a[rt][q], bq, acc[rt], 0, 0, 0);
        }
        const float bv = bd[c * 16 + m];
        #pragma unroll
        for (int rt = 0; rt < 4; ++rt)
            #pragma unroll
            for (int r = 0; r < 4; ++r)
                s[rt][r] += __expf(acc[rt][r] + bv);
    }

    #pragma unroll
    for (int rt = 0; rt < 4; ++rt)
        #pragma unroll
        for (int r = 0; r < 4; ++r)
            atomicAdd(&Sl[rt * 16 + kq * 4 + r], s[rt][r]);
    __syncthreads();
    if (tid < 64) S[(size_t)hv * BT + r0 + tid] = Sl[tid];
}

// ---------------------------------------------------------------------------
// Kernel 4 (target + final fused): per row, dot h with the target's W column
// (direct from bf16 frags, 32 thr/row), then ppl = exp(log(sum S) - logit).
// S is complete (k_dense retired before this launch).
// ---------------------------------------------------------------------------
__global__ __launch_bounds__(256) void k_target(
    const u16*   __restrict__ Hb,
    const u16*   __restrict__ Wf,
    const float* __restrict__ bd,
    const int*   __restrict__ tgt,
    const float* __restrict__ S,     // [8][BT]
    float*       __restrict__ out)   // [BT]
{
    const int tid = threadIdx.x;
    const int row = blockIdx.x * 8 + (tid >> 5);
    const int t   = tid & 31;
    const int q   = t >> 2, lq = t & 3;
    const int v   = tgt[row];
    const int c   = v >> 4, vm = v & 15;
    const int kb  = q * 32 + lq * 8;

    v8s h  = *(const v8s*)(Hb + (size_t)row * HIDN + kb);
    v8s wv = *(const v8s*)(Wf + (((size_t)c * 8 + q) * 64 + lq * 16 + vm) * 8);
    float acc = 0.0f;
    #pragma unroll
    for (int j = 0; j < 8; ++j)
        acc = fmaf(bf2f((u16)h[j]), bf2f((u16)wv[j]), acc);
    #pragma unroll
    for (int off = 16; off >= 1; off >>= 1)
        acc += __shfl_down(acc, off, 32);
    if (t == 0) {
        float tlv = acc + bd[v];
        float sum = 0.0f;
        #pragma unroll
        for (int p = 0; p < 8; ++p) sum += S[(size_t)p * BT + row];
        out[row] = __expf(__logf(sum) - tlv);
    }
}

// ---------------------------------------------------------------------------
extern "C" void kernel_launch(void* const* d_in, const int* in_sizes, int n_in,
                              void* d_out, int out_size, void* d_ws, size_t ws_size,
                              hipStream_t stream) {
    const int*   input   = (const int*)  d_in[0];   // [B,T]
    const int*   targets = (const int*)  d_in[1];   // [B,T]
    const float* E       = (const float*)d_in[2];   // [VOCAB,HID]
    const float* W_lstm  = (const float*)d_in[3];   // [2H,4H]
    const float* b_lstm  = (const float*)d_in[4];   // [4H]
    const float* W_dense = (const float*)d_in[5];   // [HID,VOCAB]
    const float* b_dense = (const float*)d_in[6];   // [VOCAB]
    float* out = (float*)d_out;                     // [B,T] perplexity

    // Workspace (< 19.3 MB; 20 MB proven in earlier rounds):
    //  [0,16M):            gx fp32 [BT][GATES]; Wf (5.12 MB) reuses this
    //                      region after k_plstm consumes gx (stream-ordered).
    //  [16M,18M):          Hb bf16 [BT][HIDN]
    //  [18M,+512K):        Whf (h-part frags)
    //  [18.5M,+512K):      Wxf (x-part frags)
    //  [19M,+64K):         Hx bf16 [2][BN][HIDN] exchange
    //  [19M+64K,+128K):    S fp32 [8][BT]
    //  [19M+192K,+1K):     bar u32 [4*64] (zeroed by k_wfrag2 block 0)
    char* ws = (char*)d_ws;
    float* gx  = (float*)ws;
    u16*   Wf  = (u16*)ws;
    u16*   Hb  = (u16*)(ws + ((size_t)16 << 20));
    u16*   Whf = (u16*)(ws + ((size_t)18 << 20));
    u16*   Wxf = (u16*)(ws + ((size_t)18 << 20) + ((size_t)512 << 10));
    u16*   Hx  = (u16*)(ws + ((size_t)19 << 20));
    float* S   = (float*)(ws + ((size_t)19 << 20) + ((size_t)64 << 10));
    u32*   bar = (u32*)  (ws + ((size_t)19 << 20) + ((size_t)192 << 10));

    k_wfrag2<<<128,      256, 0, stream>>>(W_lstm, Wxf, Whf, bar);
    k_xgates<<<BT / 16,  256, 0, stream>>>(input, E, Wxf, b_lstm, gx);
    k_plstm <<<64,       256, 0, stream>>>(Whf, gx, Hx, Hb, bar);
    k_wfrag <<<NCT,      256, 0, stream>>>(W_dense, Wf, VOCABN);   // reuses gx
    k_dense <<<512,      256, 0, stream>>>(Hb, Wf, b_dense, S);
    k_target<<<BT / 8,   256, 0, stream>>>(Hb, Wf, b_dense, targets, S, out);
}

// Round 15
// 356.594 us; speedup vs baseline: 1.3117x; 1.0124x over previous
//
#include <hip/hip_runtime.h>
#include <math.h>

// Problem constants (reference: VOCAB=10000, HID=256, B=64, T=64)
#define VOCABN 10000
#define HIDN   256
#define GATES  1024   // 4*HID
#define BN     64
#define TN     64
#define BT     4096   // B*T
#define NCT    625    // vocab col-tiles of 16 (10000 = 625*16 exactly)

typedef unsigned int       u32;
typedef unsigned short     u16;
typedef unsigned long long u64;
typedef float v4f __attribute__((ext_vector_type(4)));
typedef short v8s __attribute__((ext_vector_type(8)));

__device__ __forceinline__ float bf2f(u16 u) {
    return __uint_as_float(((u32)u) << 16);
}
__device__ __forceinline__ u16 f2bf(float f) {          // round-to-nearest-even
    u32 u = __float_as_uint(f);
    u += 0x7FFFu + ((u >> 16) & 1u);
    return (u16)(u >> 16);
}
__device__ __forceinline__ float fast_sigmoid(float x) {
    return 1.0f / (1.0f + __expf(-x));
}
__device__ __forceinline__ float fast_tanh(float x) {
    float e = __expf(-2.0f * fabsf(x));
    float t = (1.0f - e) / (1.0f + e);
    return copysignf(t, x);
}
__device__ __forceinline__ u64 llc_load(const u64* p) {
    return __hip_atomic_load(p, __ATOMIC_RELAXED, __HIP_MEMORY_SCOPE_AGENT);
}
__device__ __forceinline__ void llc_store(u64* p, u64 v) {
    __hip_atomic_store(p, v, __ATOMIC_RELAXED, __HIP_MEMORY_SCOPE_AGENT);
}
__device__ __forceinline__ u32 cnt_add(u32* p) {
    return __hip_atomic_fetch_add(p, 1u, __ATOMIC_RELAXED,
                                  __HIP_MEMORY_SCOPE_AGENT);
}
__device__ __forceinline__ u32 cnt_read(u32* p) {
    return __hip_atomic_load(p, __ATOMIC_RELAXED, __HIP_MEMORY_SCOPE_AGENT);
}

// ---------------------------------------------------------------------------
// fp32 [HIDN][ncols] tile c -> bf16 MFMA B-fragment layout [c][8 q][64 l][8].
// Fragment (c,q), lane l holds B[k = q*32 + (l>>4)*8 + j][n = c*16 + (l&15)].
// Plain uint4 stores (writer-L2 cached; cross-kernel visibility via the
// end-of-dispatch flush — consumers are always later launches).
// ---------------------------------------------------------------------------
__device__ __forceinline__ void wfrag_dev(
    const float* __restrict__ src, u16* __restrict__ dst, int ncols, int c,
    int t, u16 lt[HIDN][16])
{
    const float* s = src + (size_t)t * ncols + c * 16;
    #pragma unroll
    for (int j4 = 0; j4 < 4; ++j4) {
        float4 v = *(const float4*)(s + j4 * 4);
        lt[t][j4*4+0] = f2bf(v.x);
        lt[t][j4*4+1] = f2bf(v.y);
        lt[t][j4*4+2] = f2bf(v.z);
        lt[t][j4*4+3] = f2bf(v.w);
    }
    __syncthreads();
    #pragma unroll
    for (int h = 0; h < 2; ++h) {
        int f = t + h * 256;             // frag id = q*64 + l
        int q = f >> 6, l = f & 63;
        int m = l & 15, kb = q * 32 + ((l >> 4) & 3) * 8;
        u32 w[4];
        #pragma unroll
        for (int j = 0; j < 4; ++j)
            w[j] = (u32)lt[kb + 2*j][m] | ((u32)lt[kb + 2*j + 1][m] << 16);
        *(uint4*)(dst + (((size_t)c * 8 + q) * 64 + l) * 8) =
            make_uint4(w[0], w[1], w[2], w[3]);
    }
}

// ---------------------------------------------------------------------------
// wfrag for both W_lstm halves (128 blocks) — fallback-path prep. Block 0
// also zeroes the plstm barrier array.
// ---------------------------------------------------------------------------
__global__ __launch_bounds__(256) void k_wfrag2(
    const float* __restrict__ W_lstm,
    u16* __restrict__ Wxf, u16* __restrict__ Whf,
    u32* __restrict__ bar)           // [256] u32 (4 rg counters, 64-strided)
{
    __shared__ u16 lt[HIDN][16];
    const int bid = blockIdx.x;
    if (bid == 0) bar[threadIdx.x] = 0u;
    if (bid < 64)
        wfrag_dev(W_lstm, Wxf, GATES, bid, threadIdx.x, lt);
    else
        wfrag_dev(W_lstm + (size_t)HIDN * GATES, Whf, GATES, bid - 64,
                  threadIdx.x, lt);
}

// ---------------------------------------------------------------------------
// ALL THREE weight transforms in one launch (753 blocks) — wide-ws path.
//   0..63: W_lstm x-part -> Wxf | 64..127: h-part -> Whf | 128..752: W_dense
// Block 0 zeroes the plstm barrier array.
// ---------------------------------------------------------------------------
__global__ __launch_bounds__(256) void k_wfrag3(
    const float* __restrict__ W_lstm,
    const float* __restrict__ W_dense,
    u16* __restrict__ Wxf, u16* __restrict__ Whf, u16* __restrict__ Wf,
    u32* __restrict__ bar)
{
    __shared__ u16 lt[HIDN][16];
    const int bid = blockIdx.x;
    if (bid == 0) bar[threadIdx.x] = 0u;
    if (bid < 64)
        wfrag_dev(W_lstm, Wxf, GATES, bid, threadIdx.x, lt);
    else if (bid < 128)
        wfrag_dev(W_lstm + (size_t)HIDN * GATES, Whf, GATES, bid - 64,
                  threadIdx.x, lt);
    else
        wfrag_dev(W_dense, Wf, VOCABN, bid - 128, threadIdx.x, lt);
}

// ---------------------------------------------------------------------------
// wfrag for W_dense (625 blocks) — fallback path, runs AFTER plstm (Wf
// aliases gx there).
// ---------------------------------------------------------------------------
__global__ __launch_bounds__(256) void k_wfrag(
    const float* __restrict__ src,   // [HIDN][ncols]
    u16*         __restrict__ dst,   // [nct][8][64][8]
    int ncols)
{
    __shared__ u16 lt[HIDN][16];
    wfrag_dev(src, dst, ncols, blockIdx.x, threadIdx.x, lt);
}

// ---------------------------------------------------------------------------
// Kernel 1 (MFMA): gates_x = E[idx] @ W_x + b_lstm. 256 blocks x 16 rows.
// gx stays fp32: bf16 gx cost plstm +14us (R9 vs R10 A/B).
// ---------------------------------------------------------------------------
__global__ __launch_bounds__(256) void k_xgates(
    const int*   __restrict__ idx,   // [BT]
    const float* __restrict__ E,     // [VOCAB][HIDN]
    const u16*   __restrict__ Wxf,   // [64][8][64][8]
    const float* __restrict__ bl,    // [GATES]
    float*       __restrict__ gx)    // [BT][GATES]
{
    const int r0   = blockIdx.x * 16;
    const int tid  = threadIdx.x;
    const int w    = tid >> 6, lane = tid & 63;
    const int m    = lane & 15, quad = lane >> 4;

    v8s a[8];
    {
        const float* e = E + (size_t)idx[r0 + m] * HIDN + quad * 8;
        #pragma unroll
        for (int q = 0; q < 8; ++q) {
            float4 x0 = *(const float4*)(e + q * 32);
            float4 x1 = *(const float4*)(e + q * 32 + 4);
            uint4 t4 = make_uint4(
                (u32)f2bf(x0.x) | ((u32)f2bf(x0.y) << 16),
                (u32)f2bf(x0.z) | ((u32)f2bf(x0.w) << 16),
                (u32)f2bf(x1.x) | ((u32)f2bf(x1.y) << 16),
                (u32)f2bf(x1.z) | ((u32)f2bf(x1.w) << 16));
            a[q] = *(v8s*)&t4;
        }
    }

    for (int c = w; c < GATES / 16; c += 4) {
        v4f acc = {0.f, 0.f, 0.f, 0.f};
        #pragma unroll
        for (int q = 0; q < 8; ++q) {
            v8s b = *(const v8s*)(Wxf + (((size_t)c * 8 + q) * 64 + lane) * 8);
            acc = __builtin_amdgcn_mfma_f32_16x16x32_bf16(a[q], b, acc, 0, 0, 0);
        }
        const int col = c * 16 + m;
        const float bv = bl[col];
        #pragma unroll
        for (int r = 0; r < 4; ++r)   // D: col=lane&15, row=quad*4+r (m89/m91)
            gx[(size_t)(r0 + quad * 4 + r) * GATES + col] = acc[r] + bv;
    }
}

// ---------------------------------------------------------------------------
// Kernel 2 (persistent MFMA LSTM — R10/R14's proven 209us config VERBATIM):
// 64 blocks = 4 row-groups(16 rows) x 16 unit-slices. W_h slice LDS-resident.
// Cross-block h-exchange through the LLC ONLY via relaxed agent u64 ops.
// Counter barrier per step (flag-array variant was +11us, R12 A/B).
// Runs ALONE (R7/R8: co-running dense cost this kernel 1.7x).
// ---------------------------------------------------------------------------
__global__ __launch_bounds__(256) void k_plstm(
    const u16*   __restrict__ Whf,   // [64 ct][8][64][8] h-part frags
    const float* __restrict__ gx,    // [BT][GATES]
    u16*                      Hx,    // [2][BN][HIDN] bf16 exchange (LLC)
    u16*         __restrict__ Hb,    // [BT][HIDN] bf16 output
    u32*                      bar)   // counters (stride 64), zeroed by prep
{
    __shared__ uint4 Wl4[4 * 512];       // 32 KB: [ct][8 q][64 l][8] u16
    __shared__ float gl[4][16][16];      // 4 KB gate exchange

    const int tid  = threadIdx.x;
    const int rg   = blockIdx.x >> 4;    // row group: batch rows rg*16..+15
    const int ns   = blockIdx.x & 15;    // unit slice: units ns*16..+15
    const int u0   = ns * 16;
    const int w    = tid >> 6;           // wave = gate type (i,j,f,o)
    const int lane = tid & 63;
    const int m    = lane & 15, kq = lane >> 4;

    {   // load W_h slice: tiles c = w'*16 + ns, 8 KB contiguous each
        const uint4* src = (const uint4*)Whf;
        #pragma unroll
        for (int i = 0; i < 8; ++i) {
            int e  = tid + i * 256;          // [0, 2048)
            int ct = e >> 9, off = e & 511;  // 512 uint4 per tile
            Wl4[e] = src[(size_t)(ct * 16 + ns) * 512 + off];
        }
    }
    {   // zero gate-exchange so t=0 reads 0 for the h@W_h term
        float* g0 = (float*)gl;
        #pragma unroll
        for (int j = 0; j < 4; ++j) g0[tid * 4 + j] = 0.0f;
    }
    __syncthreads();

    const u16* Wl = (const u16*)Wl4;

    const int r = tid >> 4, u = tid & 15;
    const int b = rg * 16 + r;                       // batch row
    const float* gxp = gx + (size_t)b * TN * GATES + u0 + u;
    u16* hbp = Hb + (size_t)b * TN * HIDN + u0 + u;
    const int hxw = b * HIDN + u0 + u;               // Hx elem offset (in-buf)
    const int aoff = (rg * 16 + m) * HIDN + kq * 8;  // a-frag elem offset

    float cstate = 0.0f;
    float4 gxr;
    gxr.x = gxp[0]; gxr.y = gxp[256]; gxr.z = gxp[512]; gxr.w = gxp[768];

    for (int t = 0; t < TN; ++t) {
        // prefetch next step's x-gates early (hide HBM latency behind MFMA)
        float4 gxn = gxr;
        if (t + 1 < TN) {
            const float* p = gxp + (size_t)(t + 1) * GATES;
            gxn.x = p[0]; gxn.y = p[256]; gxn.z = p[512]; gxn.w = p[768];
        }

        if (t > 0) {
            // a-frags from LLC: relaxed agent u64 atomic loads (sc0 sc1)
            const u64* hsrc = (const u64*)(Hx + (t & 1) * (BN * HIDN) + aoff);
            v4f acc = {0.f, 0.f, 0.f, 0.f};
            #pragma unroll
            for (int q = 0; q < 8; ++q) {
                union { u64 d[2]; v8s v; } av;
                av.d[0] = llc_load(hsrc + q * 8);
                av.d[1] = llc_load(hsrc + q * 8 + 1);
                v8s bf = *(const v8s*)(Wl + ((w * 8 + q) * 64 + lane) * 8);
                acc = __builtin_amdgcn_mfma_f32_16x16x32_bf16(av.v, bf, acc, 0, 0, 0);
            }
            #pragma unroll
            for (int rr = 0; rr < 4; ++rr)   // row = kq*4+rr, col(unit) = m
                gl[w][kq * 4 + rr][m] = acc[rr];
        }
        __syncthreads();

        {   // cell update for (r, u); c stays in a register
            float ai = gl[0][r][u] + gxr.x;
            float aj = gl[1][r][u] + gxr.y;
            float af = gl[2][r][u] + gxr.z;
            float ao = gl[3][r][u] + gxr.w;
            float ig = fast_sigmoid(ai);
            float fg = fast_sigmoid(af + 1.0f);      // forget_bias = 1.0
            float og = fast_sigmoid(ao);
            float jt = fast_tanh(aj);
            cstate = fg * cstate + ig * jt;
            float hn = og * fast_tanh(cstate);
            u32 hv = f2bf(hn);
            hbp[(size_t)t * HIDN] = (u16)hv;

            if (t + 1 < TN) {
                // pack 4 consecutive units (same row, lanes tid..tid+3) into
                // one u64 and publish via relaxed agent atomic store -> LLC
                u32 p1 = __shfl_down(hv, 1);
                u32 p2 = __shfl_down(hv, 2);
                u32 p3 = __shfl_down(hv, 3);
                if ((tid & 3) == 0) {
                    u64 pk = (u64)(hv | (p1 << 16))
                           | ((u64)(p2 | (p3 << 16)) << 32);
                    u64* dst = (u64*)(Hx + (((t & 1) ^ 1) * (BN * HIDN)) + hxw);
                    llc_store(dst, pk);
                }
            }
        }

        if (t + 1 < TN) {
            __syncthreads();   // per-wave vmcnt(0) before s_barrier: all
                               // publish stores have reached the LLC
            if (tid == 0) {
                cnt_add(&bar[rg * 64]);
                u32 tgt = (u32)(t + 1) * 16u;
                while (cnt_read(&bar[rg * 64]) < tgt)
                    __builtin_amdgcn_s_sleep(1);
            }
            __syncthreads();   // broadcast release; also orders next gl writes
        }
        gxr = gxn;
    }
}

// ---------------------------------------------------------------------------
// Kernel 3 (MFMA dense, 8-way vocab split — R14 verbatim): 512 blocks =
// 64 row-groups(64 rows, 4 register-resident a-frag row-tiles) x 8 vocab
// eighths (~640 KB Wf each, L2-resident per XCD under round-robin %8).
// ---------------------------------------------------------------------------
__global__ __launch_bounds__(256, 1) void k_dense(
    const u16*   __restrict__ Hb,    // [BT][HIDN] bf16
    const u16*   __restrict__ Wf,    // [625][8][64][8]
    const float* __restrict__ bd,    // [VOCAB]
    float*       __restrict__ S)     // [8][BT] partial sumexp
{
    __shared__ float Sl[64];
    const int bid = blockIdx.x;
    const int hv  = bid & 7;                    // vocab eighth (XCD-aligned)
    const int rg  = bid >> 3;                   // 0..63
    const int r0  = rg * 64;
    const int tid = threadIdx.x;
    const int w   = tid >> 6, lane = tid & 63;
    const int m   = lane & 15, kq = lane >> 4;

    if (tid < 64) Sl[tid] = 0.0f;

    v8s a[4][8];
    #pragma unroll
    for (int rt = 0; rt < 4; ++rt) {
        const u16* hrow = Hb + (size_t)(r0 + rt * 16 + m) * HIDN + kq * 8;
        #pragma unroll
        for (int q = 0; q < 8; ++q)
            a[rt][q] = *(const v8s*)(hrow + q * 32);
    }
    __syncthreads();

    float s[4][4] = {{0.f,0.f,0.f,0.f},{0.f,0.f,0.f,0.f},
                     {0.f,0.f,0.f,0.f},{0.f,0.f,0.f,0.f}};
    const int cbeg = (hv * NCT) >> 3;
    const int cend = ((hv + 1) * NCT) >> 3;
    for (int c = cbeg + w; c < cend; c += 4) {
        v4f acc[4] = {{0.f,0.f,0.f,0.f},{0.f,0.f,0.f,0.f},
                      {0.f,0.f,0.f,0.f},{0.f,0.f,0.f,0.f}};
        #pragma unroll
        for (int q = 0; q < 8; ++q) {
            v8s bq = *(const v8s*)(Wf + (((size_t)c * 8 + q) * 64 + lane) * 8);
            #pragma unroll
            for (int rt = 0; rt < 4; ++rt)
                acc[rt] = __builtin_amdgcn_mfma_f32_16x16x32_bf16(
                              a[rt][q], bq, acc[rt], 0, 0, 0);
        }
        const float bv = bd[c * 16 + m];
        #pragma unroll
        for (int rt = 0; rt < 4; ++rt)
            #pragma unroll
            for (int r = 0; r < 4; ++r)
                s[rt][r] += __expf(acc[rt][r] + bv);
    }

    #pragma unroll
    for (int rt = 0; rt < 4; ++rt)
        #pragma unroll
        for (int r = 0; r < 4; ++r)
            atomicAdd(&Sl[rt * 16 + kq * 4 + r], s[rt][r]);
    __syncthreads();
    if (tid < 64) S[(size_t)hv * BT + r0 + tid] = Sl[tid];
}

// ---------------------------------------------------------------------------
// Kernel 4 (target + final fused — R14 verbatim): per row, dot h with the
// target's W column (32 thr/row), then ppl = exp(log(sum S) - logit).
// ---------------------------------------------------------------------------
__global__ __launch_bounds__(256) void k_target(
    const u16*   __restrict__ Hb,
    const u16*   __restrict__ Wf,
    const float* __restrict__ bd,
    const int*   __restrict__ tgt,
    const float* __restrict__ S,     // [8][BT]
    float*       __restrict__ out)   // [BT]
{
    const int tid = threadIdx.x;
    const int row = blockIdx.x * 8 + (tid >> 5);
    const int t   = tid & 31;
    const int q   = t >> 2, lq = t & 3;
    const int v   = tgt[row];
    const int c   = v >> 4, vm = v & 15;
    const int kb  = q * 32 + lq * 8;

    v8s h  = *(const v8s*)(Hb + (size_t)row * HIDN + kb);
    v8s wv = *(const v8s*)(Wf + (((size_t)c * 8 + q) * 64 + lq * 16 + vm) * 8);
    float acc = 0.0f;
    #pragma unroll
    for (int j = 0; j < 8; ++j)
        acc = fmaf(bf2f((u16)h[j]), bf2f((u16)wv[j]), acc);
    #pragma unroll
    for (int off = 16; off >= 1; off >>= 1)
        acc += __shfl_down(acc, off, 32);
    if (t == 0) {
        float tlv = acc + bd[v];
        float sum = 0.0f;
        #pragma unroll
        for (int p = 0; p < 8; ++p) sum += S[(size_t)p * BT + row];
        out[row] = __expf(__logf(sum) - tlv);
    }
}

// ---------------------------------------------------------------------------
extern "C" void kernel_launch(void* const* d_in, const int* in_sizes, int n_in,
                              void* d_out, int out_size, void* d_ws, size_t ws_size,
                              hipStream_t stream) {
    const int*   input   = (const int*)  d_in[0];   // [B,T]
    const int*   targets = (const int*)  d_in[1];   // [B,T]
    const float* E       = (const float*)d_in[2];   // [VOCAB,HID]
    const float* W_lstm  = (const float*)d_in[3];   // [2H,4H]
    const float* b_lstm  = (const float*)d_in[4];   // [4H]
    const float* W_dense = (const float*)d_in[5];   // [HID,VOCAB]
    const float* b_dense = (const float*)d_in[6];   // [VOCAB]
    float* out = (float*)d_out;                     // [B,T] perplexity

    char* ws = (char*)d_ws;
    const bool wide = (ws_size >= ((size_t)25 << 20));

    if (wide) {
        // 5-node layout: Wf gets its own region; ALL weight transforms in
        // one prep node before xgates. (~24.5 MB)
        //  [0,16M): gx | [16M,21.12M): Wf | [21.25M,23.25M): Hb
        //  [23.25M,+512K): Whf | [23.75M,+512K): Wxf | [24.25M,+64K): Hx
        //  [24.25M+64K,+128K): S | [24.25M+192K,+1K): bar
        float* gx  = (float*)ws;
        u16*   Wf  = (u16*)(ws + ((size_t)16 << 20));
        u16*   Hb  = (u16*)(ws + ((size_t)21 << 20) + ((size_t)256 << 10));
        u16*   Whf = (u16*)(ws + ((size_t)23 << 20) + ((size_t)256 << 10));
        u16*   Wxf = (u16*)(ws + ((size_t)23 << 20) + ((size_t)768 << 10));
        u16*   Hx  = (u16*)(ws + ((size_t)24 << 20) + ((size_t)256 << 10));
        float* S   = (float*)(ws + ((size_t)24 << 20) + ((size_t)320 << 10));
        u32*   bar = (u32*)  (ws + ((size_t)24 << 20) + ((size_t)448 << 10));

        k_wfrag3<<<753,     256, 0, stream>>>(W_lstm, W_dense, Wxf, Whf, Wf, bar);
        k_xgates<<<BT / 16, 256, 0, stream>>>(input, E, Wxf, b_lstm, gx);
        k_plstm <<<64,      256, 0, stream>>>(Whf, gx, Hx, Hb, bar);
        k_dense <<<512,     256, 0, stream>>>(Hb, Wf, b_dense, S);
        k_target<<<BT / 8,  256, 0, stream>>>(Hb, Wf, b_dense, targets, S, out);
    } else {
        // 6-node fallback — R14 layout verbatim (Wf aliases gx after plstm).
        float* gx  = (float*)ws;
        u16*   Wf  = (u16*)ws;
        u16*   Hb  = (u16*)(ws + ((size_t)16 << 20));
        u16*   Whf = (u16*)(ws + ((size_t)18 << 20));
        u16*   Wxf = (u16*)(ws + ((size_t)18 << 20) + ((size_t)512 << 10));
        u16*   Hx  = (u16*)(ws + ((size_t)19 << 20));
        float* S   = (float*)(ws + ((size_t)19 << 20) + ((size_t)64 << 10));
        u32*   bar = (u32*)  (ws + ((size_t)19 << 20) + ((size_t)192 << 10));

        k_wfrag2<<<128,     256, 0, stream>>>(W_lstm, Wxf, Whf, bar);
        k_xgates<<<BT / 16, 256, 0, stream>>>(input, E, Wxf, b_lstm, gx);
        k_plstm <<<64,      256, 0, stream>>>(Whf, gx, Hx, Hb, bar);
        k_wfrag <<<NCT,     256, 0, stream>>>(W_dense, Wf, VOCABN);
        k_dense <<<512,     256, 0, stream>>>(Hb, Wf, b_dense, S);
        k_target<<<BT / 8,  256, 0, stream>>>(Hb, Wf, b_dense, targets, S, out);
    }
}